// Round 5
// baseline (633.889 us; speedup 1.0000x reference)
//
#include <hip/hip_runtime.h>
#include <math.h>

#define DD    128
#define TWOD  256
#define FOURD 512
#define NBN   30
#define BQ    4096
#define FEWN  5
#define NSYM  200000
#define NGATE 1024   // 256 live units x 4 gates (units 256..511 dead)
#define ULIVE 256
#define TOTU  (2 * BQ + 2 * FEWN)   // 8202 row-units
#define MQ    8192                  // query rows (2 paths x 4096)
#define MPAD  8320                  // 65 * 128 (queries + supports + pad)
#define UPB   4                     // units per block (neighbor kernel)
#define PSTR  136                   // padded bf16 row stride (128 + 8)

typedef short bf16x8 __attribute__((ext_vector_type(8)));
typedef float f32x4 __attribute__((ext_vector_type(4)));

__device__ __forceinline__ float sigmoidf_(float x) { return 1.0f / (1.0f + expf(-x)); }

__device__ __forceinline__ float ftanh(float x) {
    float e = __expf(2.0f * x);
    return 1.0f - 2.0f / (e + 1.0f);
}

__device__ __forceinline__ unsigned short f2bf(float f) {
    unsigned int u = __float_as_uint(f);
    unsigned int r = (u + 0x7fffu + ((u >> 16) & 1u)) >> 16;
    return (unsigned short)r;
}

__device__ __forceinline__ float bf2f(unsigned short s) {
    return __uint_as_float(((unsigned int)s) << 16);
}

__device__ __forceinline__ bf16x8 pack8(float4 a, float4 b) {
    union { bf16x8 v; unsigned int u[4]; } r;
    r.u[0] = ((__float_as_uint(a.x) + 0x8000u) >> 16) | ((__float_as_uint(a.y) + 0x8000u) & 0xffff0000u);
    r.u[1] = ((__float_as_uint(a.z) + 0x8000u) >> 16) | ((__float_as_uint(a.w) + 0x8000u) & 0xffff0000u);
    r.u[2] = ((__float_as_uint(b.x) + 0x8000u) >> 16) | ((__float_as_uint(b.y) + 0x8000u) & 0xffff0000u);
    r.u[3] = ((__float_as_uint(b.z) + 0x8000u) >> 16) | ((__float_as_uint(b.w) + 0x8000u) & 0xffff0000u);
    return r.v;
}

__device__ __forceinline__ void gload_lds16(const void* g, void* l) {
    __builtin_amdgcn_global_load_lds((const __attribute__((address_space(1))) unsigned int*)g,
                                     (__attribute__((address_space(3))) unsigned int*)l,
                                     16, 0, 0);
}

// Stage ROWS x 32 bf16 tile into LDS (ROWS*4 16B segs, XOR-swizzled slots).
template <int ROWS>
__device__ __forceinline__ void stage_tile(const unsigned short* __restrict__ g, int stride,
                                           int k0, unsigned short* lds, int tid) {
#pragma unroll
    for (int it = 0; it < (ROWS * 4) / 256; ++it) {
        int s = it * 256 + tid;
        int row = s >> 2, slot = s & 3;
        int kg = slot ^ ((row >> 1) & 3);
        gload_lds16(g + (size_t)row * stride + k0 + kg * 8, lds + s * 8);
    }
}

__device__ __forceinline__ bf16x8 frag(const unsigned short* lds, int row, int quad) {
    int slot = quad ^ ((row >> 1) & 3);
    return *(const bf16x8*)(lds + row * 32 + slot * 8);
}

// ---------------- K0: one-time weight prep (all B matrices kept [n][k]) --------
__global__ __launch_bounds__(256) void k_prep(
    const float* __restrict__ Wih, const float* __restrict__ Whh,
    const float* __restrict__ bih, const float* __restrict__ bhh,
    const float* __restrict__ p1W, const float* __restrict__ p2W,
    const float* __restrict__ nW, const float* __restrict__ nvW,
    unsigned short* __restrict__ Wqbf, unsigned short* __restrict__ Whrbf,
    float* __restrict__ biasR,
    unsigned short* __restrict__ p1Wbf, unsigned short* __restrict__ p2Wbf,
    unsigned short* __restrict__ Nbf)
{
    int idx = blockIdx.x * 256 + threadIdx.x;
    int stride = gridDim.x * 256;
    for (int i = idx; i < NGATE * TWOD; i += stride) {
        int n = i >> 8, k = i & 255;
        int blk = n >> 6, rem = n & 63;
        int g = rem >> 4, ul = rem & 15;
        int srcrow = g * 512 + blk * 16 + ul;
        Wqbf[i] = f2bf(Wih[srcrow * TWOD + k]);
    }
    for (int i = idx; i < NGATE * FOURD; i += stride) {
        int n = i >> 9, k = i & 511;
        int blk = n >> 6, rem = n & 63;
        int g = rem >> 4, ul = rem & 15;
        int srcrow = g * 512 + blk * 16 + ul;
        Whrbf[i] = f2bf(Whh[srcrow * FOURD + k]);
    }
    for (int n = idx; n < NGATE; n += stride) {
        int blk = n >> 6, rem = n & 63;
        int g = rem >> 4, ul = rem & 15;
        int srcrow = g * 512 + blk * 16 + ul;
        biasR[n] = bih[srcrow] + bhh[srcrow];
    }
    for (int i = idx; i < FOURD * TWOD; i += stride) p1Wbf[i] = f2bf(p1W[i]);   // [512][256]
    for (int i = idx; i < TWOD * FOURD; i += stride) p2Wbf[i] = f2bf(p2W[i]);   // [256][512]
    for (int i = idx; i < 2 * DD * TWOD; i += stride)
        Nbf[i] = f2bf((i < DD * TWOD) ? nW[i] : nvW[i - DD * TWOD]);
}

// ---------------- K1 v5: neighbor encoder, prefetch-pipelined ------------------
__device__ __forceinline__ void nb_issue(const float* __restrict__ table, const int* sidxr,
                                         int side, int colf, int rsub, float4 (*pf)[2]) {
#pragma unroll
    for (int i = 0; i < 8; ++i) {
        int row = i * 4 + rsub;
        const float* src = table + (size_t)sidxr[2 * row + side] * DD + colf;
        pf[i][0] = *(const float4*)src;
        pf[i][1] = *(const float4*)(src + 4);
    }
}

__global__ __launch_bounds__(256, 2) void k_neighbor_v5(
    const float* __restrict__ emb, const float* __restrict__ emb_var,
    const unsigned short* __restrict__ Nbf,
    const float* __restrict__ nWb, const float* __restrict__ nu,
    const float* __restrict__ nvWb, const float* __restrict__ nvu,
    const int* __restrict__ q_left, const int* __restrict__ q_right,
    const int* __restrict__ s_left, const int* __restrict__ s_right,
    float* __restrict__ XF, unsigned short* __restrict__ Xbf)
{
    const int tid  = threadIdx.x;
    const int wave = tid >> 6, lane = tid & 63;
    const int quad = lane >> 4, m15 = lane & 15;
    const int pw   = wave >> 1;          // path of this wave (MFMA phase)
    const int wn   = wave & 1;           // n-half
    const int u0   = blockIdx.x * UPB;

    __shared__ __align__(16) unsigned short Sg[4 * 32 * PSTR];
    __shared__ int   sidxL[UPB][64];
    __shared__ float aP[2][2][32];
    __shared__ float attL[2][32];

    {
        int un = tid >> 6, i = tid & 63;
        int uu_ = u0 + un; if (uu_ >= TOTU) uu_ = TOTU - 1;
        const int* conn;
        if (uu_ < BQ)                 conn = q_left  + uu_ * (NBN * 2);
        else if (uu_ < 2 * BQ)        conn = q_right + (uu_ - BQ) * (NBN * 2);
        else if (uu_ < 2 * BQ + FEWN) conn = s_left  + (uu_ - 2 * BQ) * (NBN * 2);
        else                          conn = s_right + (uu_ - 2 * BQ - FEWN) * (NBN * 2);
        sidxL[un][i] = (i < NBN * 2) ? conn[i] : NSYM;
    }

    const unsigned short* Bw = Nbf + (size_t)pw * DD * TWOD;
    const float* Wb = pw ? nvWb : nWb;
    const float* uu = pw ? nvu  : nu;
    bf16x8 Bf[4][8];
    float nb[4], un_[4];
#pragma unroll
    for (int t = 0; t < 4; ++t) {
        int n = wn * 64 + t * 16 + m15;
#pragma unroll
        for (int kt = 0; kt < 8; ++kt)
            Bf[t][kt] = *(const bf16x8*)(Bw + n * TWOD + kt * 32 + quad * 8);
        nb[t] = Wb[n];
        un_[t] = uu[n];
    }
    __syncthreads();

    // staging geometry (per wave = one of 4 row-groups)
    const float* table = (wave < 2) ? emb : emb_var;
    const int side = wave & 1;
    const int colf = (lane & 15) * 8;
    const int rsub = lane >> 4;

    float4 pf[8][2];
    nb_issue(table, sidxL[0], side, colf, rsub, pf);   // prefetch unit 0

    for (int r = 0; r < UPB; ++r) {
        const int uidx = u0 + r;

        // ---- pack prefetched rows -> LDS ----
#pragma unroll
        for (int i = 0; i < 8; ++i)
            *(bf16x8*)&Sg[(wave * 32 + i * 4 + rsub) * PSTR + colf] = pack8(pf[i][0], pf[i][1]);
        __syncthreads();

        if (r + 1 < UPB)
            nb_issue(table, sidxL[r + 1], side, colf, rsub, pf);  // overlaps compute

        // ---- MFMA: S[32x64 per wave] = cat * W^T ----
        const int pg = pw ? 2 : 0;
        f32x4 acc[2][4] = {};
#pragma unroll
        for (int kt = 0; kt < 8; ++kt) {
            const int g = (kt < 4) ? pg : pg + 1;
            const int coff = (kt & 3) * 32 + quad * 8;
            bf16x8 fa[2];
#pragma unroll
            for (int mt = 0; mt < 2; ++mt)
                fa[mt] = *(const bf16x8*)&Sg[(g * 32 + mt * 16 + m15) * PSTR + coff];
#pragma unroll
            for (int mt = 0; mt < 2; ++mt)
#pragma unroll
                for (int nt = 0; nt < 4; ++nt)
                    acc[mt][nt] = __builtin_amdgcn_mfma_f32_16x16x32_bf16(fa[mt], Bf[nt][kt], acc[mt][nt], 0, 0, 0);
        }

        // ---- epilogue: partial a[m] over this n-half ----
        {
            float part[2][4];
#pragma unroll
            for (int mt = 0; mt < 2; ++mt)
#pragma unroll
                for (int rr = 0; rr < 4; ++rr) {
                    float s = 0.f;
#pragma unroll
                    for (int nt = 0; nt < 4; ++nt)
                        s += un_[nt] * ftanh(acc[mt][nt][rr] + nb[nt]);
                    part[mt][rr] = s;
                }
#pragma unroll
            for (int off = 1; off < 16; off <<= 1)
#pragma unroll
                for (int mt = 0; mt < 2; ++mt)
#pragma unroll
                    for (int rr = 0; rr < 4; ++rr)
                        part[mt][rr] += __shfl_xor(part[mt][rr], off, 64);
            if (m15 == 0) {
#pragma unroll
                for (int mt = 0; mt < 2; ++mt)
#pragma unroll
                    for (int rr = 0; rr < 4; ++rr)
                        aP[pw][wn][mt * 16 + quad * 4 + rr] = part[mt][rr];
            }
        }
        __syncthreads();

        // ---- softmax over 30 neighbors: wave 0 -> p0, wave 2 -> p1 ----
        if ((wave & 1) == 0 && lane < 32) {
            const int p = wave >> 1;
            float sc = (lane < NBN) ? aP[p][0][lane] + aP[p][1][lane] : -1e30f;
            float mx = sc;
#pragma unroll
            for (int off = 1; off < 32; off <<= 1) mx = fmaxf(mx, __shfl_xor(mx, off, 64));
            float e = (lane < NBN) ? __expf(sc - mx) : 0.f;
            float sum = e;
#pragma unroll
            for (int off = 1; off < 32; off <<= 1) sum += __shfl_xor(sum, off, 64);
            attL[p][lane] = e / sum;
        }
        __syncthreads();

        // ---- pool ent_e (group 1 = emb[ent], both paths) + tanh + store -------
        {
            const int p = tid >> 7;
            const int d = tid & 127;
            float pool = 0.f;
#pragma unroll
            for (int k = 0; k < NBN; ++k)
                pool += attL[p][k] * bf2f(Sg[(32 + k) * PSTR + d]);
            if (uidx < TOTU) {
                size_t m; int coloff;
                if (uidx < BQ)                 { m = (size_t)p * BQ + uidx;                coloff = 0; }
                else if (uidx < 2 * BQ)        { m = (size_t)p * BQ + (uidx - BQ);         coloff = DD; }
                else if (uidx < 2 * BQ + FEWN) { m = MQ + p * FEWN + (uidx - 2 * BQ);      coloff = 0; }
                else                           { m = MQ + p * FEWN + (uidx - 2 * BQ - FEWN); coloff = DD; }
                float v = ftanh(pool);
                XF[m * TWOD + coloff + d]  = v;
                Xbf[m * TWOD + coloff + d] = f2bf(v);
            }
        }
        __syncthreads();
    }
}

// ---------------- K2a: h1 = relu(X p1W^T + b1), M=8320 N=512 K=256 -------------
__global__ __launch_bounds__(256) void k_gemm_h1(
    const unsigned short* __restrict__ Xbf, const unsigned short* __restrict__ p1Wbf,
    const float* __restrict__ p1b, unsigned short* __restrict__ H1bf)
{
    __shared__ __align__(16) unsigned short As[128 * 32];
    __shared__ __align__(16) unsigned short Bs[128 * 32];
    const int tid = threadIdx.x;
    const int wave = tid >> 6, lane = tid & 63;
    const int quad = lane >> 4, m15 = lane & 15;
    const int m0 = blockIdx.x * 128, n0 = blockIdx.y * 128;
    const int wm = wave >> 1, wn = wave & 1;

    f32x4 acc[4][4] = {};
    for (int kt = 0; kt < 8; ++kt) {
        __syncthreads();
        stage_tile<128>(Xbf + (size_t)m0 * TWOD, TWOD, kt * 32, As, tid);
        stage_tile<128>(p1Wbf + (size_t)n0 * TWOD, TWOD, kt * 32, Bs, tid);
        __syncthreads();
        bf16x8 fa[4], fb[4];
#pragma unroll
        for (int i = 0; i < 4; ++i) {
            fa[i] = frag(As, wm * 64 + i * 16 + m15, quad);
            fb[i] = frag(Bs, wn * 64 + i * 16 + m15, quad);
        }
#pragma unroll
        for (int mi = 0; mi < 4; ++mi)
#pragma unroll
            for (int ni = 0; ni < 4; ++ni)
                acc[mi][ni] = __builtin_amdgcn_mfma_f32_16x16x32_bf16(fa[mi], fb[ni], acc[mi][ni], 0, 0, 0);
    }
#pragma unroll
    for (int ni = 0; ni < 4; ++ni) {
        int col = n0 + wn * 64 + ni * 16 + m15;
        float b = p1b[col];
#pragma unroll
        for (int mi = 0; mi < 4; ++mi)
#pragma unroll
            for (int r = 0; r < 4; ++r) {
                int gm = m0 + wm * 64 + mi * 16 + quad * 4 + r;
                H1bf[(size_t)gm * FOURD + col] = f2bf(fmaxf(acc[mi][ni][r] + b, 0.f));
            }
    }
}

// ---------------- K2b: g = LN(H1 p2W^T + b2 + X), M-tile 64, N=256, K=512 ------
__global__ __launch_bounds__(256) void k_gemm_g_ln(
    const unsigned short* __restrict__ H1bf, const unsigned short* __restrict__ p2Wbf,
    const float* __restrict__ p2b, const float* __restrict__ XF,
    const float* __restrict__ ln_a, const float* __restrict__ ln_b,
    float* __restrict__ GF, unsigned short* __restrict__ Gbf)
{
    __shared__ __align__(16) unsigned short As[64 * 32];
    __shared__ __align__(16) unsigned short Bs[256 * 32];
    __shared__ float redS[4][64], redQ[4][64];
    const int tid = threadIdx.x;
    const int wave = tid >> 6, lane = tid & 63;
    const int quad = lane >> 4, m15 = lane & 15;
    const int m0 = blockIdx.x * 64;
    const int wn = wave;     // wave covers cols wn*64..+64

    f32x4 acc[4][4] = {};    // [mi][ni]
    for (int kt = 0; kt < 16; ++kt) {
        __syncthreads();
        stage_tile<64>(H1bf + (size_t)m0 * FOURD, FOURD, kt * 32, As, tid);
        stage_tile<256>(p2Wbf, FOURD, kt * 32, Bs, tid);
        __syncthreads();
        bf16x8 fa[4], fb[4];
#pragma unroll
        for (int i = 0; i < 4; ++i) {
            fa[i] = frag(As, i * 16 + m15, quad);
            fb[i] = frag(Bs, wn * 64 + i * 16 + m15, quad);
        }
#pragma unroll
        for (int mi = 0; mi < 4; ++mi)
#pragma unroll
            for (int ni = 0; ni < 4; ++ni)
                acc[mi][ni] = __builtin_amdgcn_mfma_f32_16x16x32_bf16(fa[mi], fb[ni], acc[mi][ni], 0, 0, 0);
    }
    // z = acc + b2 + X (in place)
#pragma unroll
    for (int ni = 0; ni < 4; ++ni) {
        int col = wn * 64 + ni * 16 + m15;
        float b = p2b[col];
#pragma unroll
        for (int mi = 0; mi < 4; ++mi)
#pragma unroll
            for (int r = 0; r < 4; ++r) {
                int gm = m0 + mi * 16 + quad * 4 + r;
                acc[mi][ni][r] += b + XF[(size_t)gm * TWOD + col];
            }
    }
    // per-row sum / sumsq over this wave's 64 cols
#pragma unroll
    for (int mi = 0; mi < 4; ++mi)
#pragma unroll
        for (int r = 0; r < 4; ++r) {
            float s = acc[mi][0][r] + acc[mi][1][r] + acc[mi][2][r] + acc[mi][3][r];
            float q = acc[mi][0][r] * acc[mi][0][r] + acc[mi][1][r] * acc[mi][1][r]
                    + acc[mi][2][r] * acc[mi][2][r] + acc[mi][3][r] * acc[mi][3][r];
#pragma unroll
            for (int off = 1; off < 16; off <<= 1) {
                s += __shfl_xor(s, off, 64);
                q += __shfl_xor(q, off, 64);
            }
            if (m15 == 0) {
                redS[wn][mi * 16 + quad * 4 + r] = s;
                redQ[wn][mi * 16 + quad * 4 + r] = q;
            }
        }
    __syncthreads();
#pragma unroll
    for (int mi = 0; mi < 4; ++mi)
#pragma unroll
        for (int r = 0; r < 4; ++r) {
            int row = mi * 16 + quad * 4 + r;
            float st = redS[0][row] + redS[1][row] + redS[2][row] + redS[3][row];
            float sq = redQ[0][row] + redQ[1][row] + redQ[2][row] + redQ[3][row];
            float mu = st / 256.f;
            float var = fmaxf((sq - 256.f * mu * mu) / 255.f, 0.f);
            float inv = 1.f / (sqrtf(var) + 1e-3f);
            int gm = m0 + row;
#pragma unroll
            for (int ni = 0; ni < 4; ++ni) {
                int col = wn * 64 + ni * 16 + m15;
                float o = (acc[mi][ni][r] - mu) * inv * ln_a[col] + ln_b[col];
                GF[(size_t)gm * TWOD + col]  = o;
                Gbf[(size_t)gm * TWOD + col] = f2bf(o);
            }
        }
}

// ---------------- K3: gq0^T = (G Wq^T)^T, M=8192 N=1024 K=256, bf16 out --------
__global__ __launch_bounds__(256) void k_gemm_gq0(
    const unsigned short* __restrict__ Gbf, const unsigned short* __restrict__ Wqbf,
    unsigned short* __restrict__ gq0T)
{
    __shared__ __align__(16) unsigned short As[128 * 32];
    __shared__ __align__(16) unsigned short Bs[128 * 32];
    const int tid = threadIdx.x;
    const int wave = tid >> 6, lane = tid & 63;
    const int quad = lane >> 4, m15 = lane & 15;
    const int m0 = blockIdx.x * 128, n0 = blockIdx.y * 128;
    const int wm = wave >> 1, wn = wave & 1;

    f32x4 acc[4][4] = {};
    for (int kt = 0; kt < 8; ++kt) {
        __syncthreads();
        stage_tile<128>(Gbf + (size_t)m0 * TWOD, TWOD, kt * 32, As, tid);
        stage_tile<128>(Wqbf + (size_t)n0 * TWOD, TWOD, kt * 32, Bs, tid);
        __syncthreads();
        bf16x8 fa[4], fb[4];
#pragma unroll
        for (int i = 0; i < 4; ++i) {
            fa[i] = frag(As, wm * 64 + i * 16 + m15, quad);
            fb[i] = frag(Bs, wn * 64 + i * 16 + m15, quad);
        }
#pragma unroll
        for (int mi = 0; mi < 4; ++mi)
#pragma unroll
            for (int ni = 0; ni < 4; ++ni)
                acc[mi][ni] = __builtin_amdgcn_mfma_f32_16x16x32_bf16(fa[mi], fb[ni], acc[mi][ni], 0, 0, 0);
    }
#pragma unroll
    for (int ni = 0; ni < 4; ++ni) {
        int col = n0 + wn * 64 + ni * 16 + m15;
#pragma unroll
        for (int mi = 0; mi < 4; ++mi) {
            unsigned short tb[4] __attribute__((aligned(8)));
#pragma unroll
            for (int r = 0; r < 4; ++r) tb[r] = f2bf(acc[mi][ni][r]);
            int gm = m0 + wm * 64 + mi * 16 + quad * 4;
            *(uint2*)(gq0T + (size_t)col * MQ + gm) = *(uint2*)tb;
        }
    }
}

// ---------------- K4a: LSTM step: gates = gq0 + [h|r] Whr^T, fused cell --------
__global__ __launch_bounds__(256) void k_lstm_step(
    const unsigned short* __restrict__ Abf, const unsigned short* __restrict__ Whrbf,
    const unsigned short* __restrict__ gq0T, const float* __restrict__ biasR,
    float* __restrict__ cst, float* __restrict__ hbuf)
{
    __shared__ __align__(16) unsigned short As[128 * 32];
    __shared__ __align__(16) unsigned short Bs[128 * 32];
    const int tid = threadIdx.x;
    const int wave = tid >> 6, lane = tid & 63;
    const int quad = lane >> 4, m15 = lane & 15;
    const int m0 = blockIdx.x * 128, n0 = blockIdx.y * 128;
    const int wm = wave >> 1, wn = wave & 1;

    f32x4 acc[4][4];
    // C-init: gq0 + bias
#pragma unroll
    for (int ni = 0; ni < 4; ++ni) {
        int col = n0 + wn * 64 + ni * 16 + m15;
        float b = biasR[col];
#pragma unroll
        for (int mi = 0; mi < 4; ++mi) {
            int gm = m0 + wm * 64 + mi * 16 + quad * 4;
            uint2 u = *(const uint2*)(gq0T + (size_t)col * MQ + gm);
            unsigned short* us = (unsigned short*)&u;
#pragma unroll
            for (int r = 0; r < 4; ++r) acc[mi][ni][r] = bf2f(us[r]) + b;
        }
    }
    for (int kt = 0; kt < 16; ++kt) {
        __syncthreads();
        stage_tile<128>(Abf + (size_t)m0 * FOURD, FOURD, kt * 32, As, tid);
        stage_tile<128>(Whrbf + (size_t)n0 * FOURD, FOURD, kt * 32, Bs, tid);
        __syncthreads();
        bf16x8 fa[4], fb[4];
#pragma unroll
        for (int i = 0; i < 4; ++i) {
            fa[i] = frag(As, wm * 64 + i * 16 + m15, quad);
            fb[i] = frag(Bs, wn * 64 + i * 16 + m15, quad);
        }
#pragma unroll
        for (int mi = 0; mi < 4; ++mi)
#pragma unroll
            for (int ni = 0; ni < 4; ++ni)
                acc[mi][ni] = __builtin_amdgcn_mfma_f32_16x16x32_bf16(fa[mi], fb[ni], acc[mi][ni], 0, 0, 0);
    }
    const int u = ((n0 + wn * 64) >> 2) + m15;
#pragma unroll
    for (int mi = 0; mi < 4; ++mi) {
#pragma unroll
        for (int r = 0; r < 4; ++r) {
            int gm = m0 + wm * 64 + mi * 16 + quad * 4 + r;
            size_t cidx = (size_t)gm * ULIVE + u;
            float cn = sigmoidf_(acc[mi][1][r]) * cst[cidx]
                     + sigmoidf_(acc[mi][0][r]) * tanhf(acc[mi][2][r]);
            cst[cidx]  = cn;
            hbuf[cidx] = sigmoidf_(acc[mi][3][r]) * tanhf(cn);
        }
    }
}

// ---------------- K4b: h, attention over support, write bf16 [h|r] -------------
__global__ __launch_bounds__(256) void k_lstm_attn(
    const float* __restrict__ GF, const float* __restrict__ hbuf,
    unsigned short* __restrict__ Abf, float* __restrict__ hfin)
{
    const int tid = threadIdx.x;
    const int p   = blockIdx.y;
    const int wv = tid >> 6, lane = tid & 63;
    __shared__ float sgl[FEWN][TWOD];
    for (int idx = tid; idx < FEWN * TWOD; idx += 256)
        sgl[idx >> 8][idx & 255] = GF[(size_t)(MQ + p * FEWN) * TWOD + idx];
    __syncthreads();
    const int j0 = lane * 4;
    for (int rr = 0; rr < 8; ++rr) {
        int row = blockIdx.x * 32 + wv * 8 + rr;
        size_t g = (size_t)p * BQ + row;
        float4 q4 = *(const float4*)(GF + g * TWOD + j0);
        float4 t4 = *(const float4*)(hbuf + g * ULIVE + j0);
        float h[4] __attribute__((aligned(16))) = {q4.x + t4.x, q4.y + t4.y, q4.z + t4.z, q4.w + t4.w};
        float sv[FEWN][4] __attribute__((aligned(16)));
        float pa[FEWN];
#pragma unroll
        for (int f = 0; f < FEWN; ++f) {
            *(float4*)sv[f] = *(const float4*)&sgl[f][j0];
            pa[f] = h[0] * sv[f][0] + h[1] * sv[f][1] + h[2] * sv[f][2] + h[3] * sv[f][3];
        }
#pragma unroll
        for (int off = 1; off < 64; off <<= 1)
#pragma unroll
            for (int f = 0; f < FEWN; ++f) pa[f] += __shfl_xor(pa[f], off, 64);
        float mx = pa[0];
#pragma unroll
        for (int f = 1; f < FEWN; ++f) mx = fmaxf(mx, pa[f]);
        float sum = 0.f, e[FEWN];
#pragma unroll
        for (int f = 0; f < FEWN; ++f) { e[f] = expf(pa[f] - mx); sum += e[f]; }
        float inv = 1.f / sum;
        float r4[4] __attribute__((aligned(16))) = {0.f, 0.f, 0.f, 0.f};
#pragma unroll
        for (int f = 0; f < FEWN; ++f) {
            float a = e[f] * inv;
#pragma unroll
            for (int q = 0; q < 4; ++q) r4[q] += a * sv[f][q];
        }
        unsigned short tb[4] __attribute__((aligned(8)));
#pragma unroll
        for (int q = 0; q < 4; ++q) tb[q] = f2bf(h[q]);
        *(uint2*)(Abf + g * FOURD + j0) = *(uint2*)tb;
#pragma unroll
        for (int q = 0; q < 4; ++q) tb[q] = f2bf(r4[q]);
        *(uint2*)(Abf + g * FOURD + TWOD + j0) = *(uint2*)tb;
        *(float4*)(hfin + g * TWOD + j0) = *(float4*)h;
    }
}

// ---------------- K5: final scores ---------------------------------------------
__global__ __launch_bounds__(256) void k_score(
    const float* __restrict__ hfin, const float* __restrict__ GF, float* __restrict__ out)
{
    const int tid = threadIdx.x;
    const int p   = blockIdx.y;
    __shared__ float sm[TWOD];
    if (tid < TWOD) {
        const float* s = GF + (size_t)(MQ + p * FEWN) * TWOD + tid;
        sm[tid] = (s[0] + s[TWOD] + s[2 * TWOD] + s[3 * TWOD] + s[4 * TWOD]) / 5.0f;
    }
    __syncthreads();
    const int wv = tid >> 6, lane = tid & 63;
    const int j0 = lane * 4;
    for (int rr = 0; rr < 8; ++rr) {
        int row = blockIdx.x * 32 + wv * 8 + rr;
        const float* h = hfin + ((size_t)p * BQ + row) * TWOD + j0;
        float4 h4 = *(const float4*)h;
        float4 s4 = *(const float4*)&sm[j0];
        float pv = h4.x * s4.x + h4.y * s4.y + h4.z * s4.z + h4.w * s4.w;
#pragma unroll
        for (int off = 1; off < 64; off <<= 1) pv += __shfl_xor(pv, off, 64);
        if (lane == 0) out[p * BQ + row] = pv;
    }
}

extern "C" void kernel_launch(void* const* d_in, const int* in_sizes, int n_in,
                              void* d_out, int out_size, void* d_ws, size_t ws_size,
                              hipStream_t stream)
{
    const float* emb     = (const float*)d_in[0];
    const float* emb_var = (const float*)d_in[1];
    const float* nW      = (const float*)d_in[2];
    const float* nWb     = (const float*)d_in[3];
    const float* nu      = (const float*)d_in[4];
    const float* nub     = (const float*)d_in[5];
    const float* nvW     = (const float*)d_in[6];
    const float* nvWb    = (const float*)d_in[7];
    const float* nvu     = (const float*)d_in[8];
    const float* nvub    = (const float*)d_in[9];
    const float* p1W     = (const float*)d_in[10];
    const float* p1b     = (const float*)d_in[11];
    const float* p2W     = (const float*)d_in[12];
    const float* p2b     = (const float*)d_in[13];
    const float* ln_a    = (const float*)d_in[14];
    const float* ln_b    = (const float*)d_in[15];
    const float* Wih     = (const float*)d_in[16];
    const float* Whh     = (const float*)d_in[17];
    const float* bih     = (const float*)d_in[18];
    const float* bhh     = (const float*)d_in[19];
    const int* q_left    = (const int*)d_in[20];
    const int* q_right   = (const int*)d_in[21];
    const int* s_left    = (const int*)d_in[22];
    const int* s_right   = (const int*)d_in[23];

    float* ws = (float*)d_ws;
    size_t o = 0;
    unsigned short* Wqbf  = (unsigned short*)(ws + o); o += (size_t)NGATE * TWOD / 2;   // 65536
    unsigned short* Whrbf = (unsigned short*)(ws + o); o += (size_t)NGATE * FOURD / 2;  // 262144
    float* biasR          = ws + o; o += NGATE;
    unsigned short* p1Wbf = (unsigned short*)(ws + o); o += (size_t)FOURD * TWOD / 2;
    unsigned short* p2Wbf = (unsigned short*)(ws + o); o += (size_t)TWOD * FOURD / 2;
    unsigned short* Nbf   = (unsigned short*)(ws + o); o += (size_t)2 * DD * TWOD / 2;
    float* XF             = ws + o; o += (size_t)MPAD * TWOD;        // reused as hfin
    float* GF             = ws + o; o += (size_t)MPAD * TWOD;
    unsigned short* Gbf   = (unsigned short*)(ws + o); o += (size_t)MPAD * TWOD / 2;
    float* cst            = ws + o; o += (size_t)MQ * ULIVE;
    float* hbuf           = ws + o; o += (size_t)MQ * ULIVE;
    unsigned short* Abf   = (unsigned short*)(ws + o); o += (size_t)MQ * FOURD / 2;
    // overlay region: [Xbf | H1bf] lives until g_ln; gq0T lives after
    size_t regionStart = o;
    unsigned short* Xbf   = (unsigned short*)(ws + regionStart);
    unsigned short* H1bf  = (unsigned short*)(ws + regionStart + (size_t)MPAD * TWOD / 2);
    unsigned short* gq0T  = (unsigned short*)(ws + regionStart);
    o += (size_t)NGATE * MQ / 2;   // region size = max(gq0T, Xbf+H1bf) = 4194304 floats
    float* hfin = XF;

    hipMemsetAsync(cst, 0, (size_t)MQ * ULIVE * sizeof(float), stream);
    hipMemsetAsync(Abf, 0, (size_t)MQ * FOURD * sizeof(unsigned short), stream);

    k_prep<<<dim3(1024), dim3(256), 0, stream>>>(Wih, Whh, bih, bhh, p1W, p2W, nW, nvW,
                                                 Wqbf, Whrbf, biasR, p1Wbf, p2Wbf, Nbf);
    k_neighbor_v5<<<dim3((TOTU + UPB - 1) / UPB), dim3(256), 0, stream>>>(
        emb, emb_var, Nbf, nWb, nu, nvWb, nvu,
        q_left, q_right, s_left, s_right, XF, Xbf);
    k_gemm_h1<<<dim3(MPAD / 128, 4), dim3(256), 0, stream>>>(Xbf, p1Wbf, p1b, H1bf);
    k_gemm_g_ln<<<dim3(MPAD / 64), dim3(256), 0, stream>>>(H1bf, p2Wbf, p2b, XF, ln_a, ln_b, GF, Gbf);
    k_gemm_gq0<<<dim3(MQ / 128, NGATE / 128), dim3(256), 0, stream>>>(Gbf, Wqbf, gq0T);
    for (int s = 0; s < 4; ++s) {
        k_lstm_step<<<dim3(MQ / 128, NGATE / 128), dim3(256), 0, stream>>>(Abf, Whrbf, gq0T, biasR, cst, hbuf);
        k_lstm_attn<<<dim3(BQ / 32, 2), dim3(256), 0, stream>>>(GF, hbuf, Abf, hfin);
    }
    k_score<<<dim3(BQ / 32, 2), dim3(256), 0, stream>>>(hfin, GF, (float*)d_out);
}